// Round 1
// 1624.716 us; speedup vs baseline: 1.3607x; 1.3607x over previous
//
#include <hip/hip_runtime.h>
#include <string.h>

#define B 4
#define N 16384
#define D 256
#define K 512
#define ITERS 10

typedef short short8 __attribute__((ext_vector_type(8)));
typedef float float4v __attribute__((ext_vector_type(4)));

// ---------------- host MT19937 exactly matching CPython random.seed(42); random.sample(range(16384), 512)
static void host_sample_inds(int* out) {
    static unsigned int mt[624];
    mt[0] = 19650218u;
    for (int i = 1; i < 624; i++)
        mt[i] = 1812433253u * (mt[i - 1] ^ (mt[i - 1] >> 30)) + (unsigned)i;
    {
        int i = 1, j = 0;
        for (int kk = 624; kk; kk--) {
            mt[i] = (mt[i] ^ ((mt[i - 1] ^ (mt[i - 1] >> 30)) * 1664525u)) + 42u + (unsigned)j;
            i++; j++;
            if (i >= 624) { mt[0] = mt[623]; i = 1; }
            if (j >= 1) j = 0;
        }
        for (int kk = 623; kk; kk--) {
            mt[i] = (mt[i] ^ ((mt[i - 1] ^ (mt[i - 1] >> 30)) * 1566083941u)) - (unsigned)i;
            i++;
            if (i >= 624) { mt[0] = mt[623]; i = 1; }
        }
        mt[0] = 0x80000000u;
    }
    static unsigned char seen[N];
    memset(seen, 0, sizeof(seen));
    int mti = 624;
    int got = 0;
    while (got < K) {
        if (mti >= 624) {
            for (int kk = 0; kk < 624; kk++) {
                unsigned int yy = (mt[kk] & 0x80000000u) | (mt[(kk + 1) % 624] & 0x7fffffffu);
                mt[kk] = mt[(kk + 397) % 624] ^ (yy >> 1) ^ ((yy & 1u) ? 0x9908b0dfu : 0u);
            }
            mti = 0;
        }
        unsigned int y = mt[mti++];
        y ^= y >> 11; y ^= (y << 7) & 0x9d2c5680u; y ^= (y << 15) & 0xefc60000u; y ^= y >> 18;
        unsigned int r = y >> 17;
        if (r >= (unsigned)N) continue;
        if (seen[r]) continue;
        seen[r] = 1;
        out[got++] = (int)r;
    }
}

__device__ inline void gload_lds16(const void* g, void* l) {
    __builtin_amdgcn_global_load_lds((const __attribute__((address_space(1))) void*)g,
                                     (__attribute__((address_space(3))) void*)l, 16, 0, 0);
}

__device__ inline unsigned bf16_rne(float f) {
    unsigned u = __float_as_uint(f);
    return (u + 0x7fffu + ((u >> 16) & 1u)) >> 16;
}

__device__ inline unsigned long long shfl_xor_u64(unsigned long long v, int off) {
    int lo = __shfl_xor((int)(unsigned)(v & 0xffffffffull), off);
    int hi = __shfl_xor((int)(unsigned)(v >> 32), off);
    return ((unsigned long long)(unsigned)hi << 32) | (unsigned)lo;
}

// =================== prep ===================

__global__ void k_gather_v0(const float* __restrict__ x, const int* __restrict__ inds,
                            float* __restrict__ v) {
    int bk = blockIdx.x; int b = bk / K, k = bk % K;
    int n = inds[k];
    const float4* src = (const float4*)(x + ((size_t)b * N + n) * D);
    float4* dst = (float4*)(v + ((size_t)b * K + k) * D);
    dst[threadIdx.x] = src[threadIdx.x];
}

__global__ void k_totsum(const float* __restrict__ x, float* __restrict__ totsum) {
    int b = blockIdx.y;
    int n0 = blockIdx.x * (N / 64);
    int t = threadIdx.x;
    const float* xb = x + (size_t)b * N * D;
    float s = 0.f;
    for (int n = n0; n < n0 + N / 64; n++) s += xb[(size_t)n * D + t];
    atomicAdd(&totsum[b * D + t], s);
}

// fused: rownorm + bf16 split + residual norm + lo norm. wave per row.
__global__ void k_prep(const float* __restrict__ src, unsigned short* __restrict__ cat,
                       float* __restrict__ sq, float* __restrict__ resn,
                       float* __restrict__ lon) {
    int wave = threadIdx.x >> 6, lane = threadIdx.x & 63;
    int row = blockIdx.x * 4 + wave;
    float4 f = ((const float4*)(src + (size_t)row * D))[lane];
    float comp[4] = {f.x, f.y, f.z, f.w};
    unsigned short h[4], l[4];
    float r2 = 0.f, l2 = 0.f, n2 = 0.f;
    #pragma unroll
    for (int j = 0; j < 4; j++) {
        n2 += comp[j] * comp[j];
        unsigned hi = bf16_rne(comp[j]);
        float hif = __uint_as_float(hi << 16);
        float r = comp[j] - hif;            // exact in fp32
        unsigned lo = bf16_rne(r);
        float lof = __uint_as_float(lo << 16);
        float res = r - lof;                // dropped residual
        r2 += res * res;
        l2 += lof * lof;
        h[j] = (unsigned short)hi; l[j] = (unsigned short)lo;
    }
    unsigned short* orow = cat + (size_t)row * 512;
    *(ushort4*)&orow[lane * 4] = make_ushort4(h[0], h[1], h[2], h[3]);
    *(ushort4*)&orow[256 + lane * 4] = make_ushort4(l[0], l[1], l[2], l[3]);
    #pragma unroll
    for (int off = 32; off; off >>= 1) {
        r2 += __shfl_xor(r2, off);
        l2 += __shfl_xor(l2, off);
        n2 += __shfl_xor(n2, off);
    }
    if (lane == 0) { sq[row] = n2; resn[row] = sqrtf(r2); lon[row] = sqrtf(l2); }
}

// per-batch maxes: ||v||, ||v residual||, ||v lo||
__global__ void k_errmax(const float* __restrict__ v2, const float* __restrict__ vres,
                         const float* __restrict__ vlo,
                         float* __restrict__ vmaxs, float* __restrict__ vresmaxs,
                         float* __restrict__ vlomaxs) {
    __shared__ float s1[256], s2[256], s3[256];
    int b = blockIdx.x, t = threadIdx.x;
    s1[t] = fmaxf(sqrtf(v2[b * K + t]), sqrtf(v2[b * K + 256 + t]));
    s2[t] = fmaxf(vres[b * K + t], vres[b * K + 256 + t]);
    s3[t] = fmaxf(vlo[b * K + t], vlo[b * K + 256 + t]);
    __syncthreads();
    for (int s = 128; s; s >>= 1) {
        if (t < s) {
            s1[t] = fmaxf(s1[t], s1[t + s]);
            s2[t] = fmaxf(s2[t], s2[t + s]);
            s3[t] = fmaxf(s3[t], s3[t + s]);
        }
        __syncthreads();
    }
    if (t == 0) { vmaxs[b] = s1[0]; vresmaxs[b] = s2[0]; vlomaxs[b] = s3[0]; }
}

__global__ void k_transpose(const float* __restrict__ v, float* __restrict__ vT) {
    int idx = blockIdx.x * 256 + threadIdx.x;   // B*K*D
    int d = idx & 255, c = (idx >> 8) & 511, b = idx >> 17;
    vT[((size_t)b * D + d) * K + c] = v[idx];
}

// =================== fused MFMA GEMM + full 512-center top-2 + assign ===================
// merged-chunk version: one block computes 128 points x ALL 512 centers.
//  - 48-step (4 ch x 12 kt) double-buffered K-loop; prefetch crosses chunk boundaries
//    (12 even -> cur = kt&1 stays consistent across chunks)
//  - running per-row top-2 kept in registers as u64 keys (dist_bits<<32)|center:
//    for dist >= 0 fp32, u64 order == lexicographic (dist, index) order, identical to
//    the old chunked merge semantics (selection is order-independent in a total order)
//  - epilogue writes assign/counts/refine directly (k_reduce2 + pvals/pinds removed)
__global__ __launch_bounds__(256, 2) void k_gemm_assign(
    const unsigned short* __restrict__ xcat, const unsigned short* __restrict__ vcat,
    const float* __restrict__ x2, const float* __restrict__ v2,
    const float* __restrict__ xres, const float* __restrict__ xlo,
    const float* __restrict__ vmaxs, const float* __restrict__ vresmaxs,
    const float* __restrict__ vlomaxs,
    int* __restrict__ assign, int* __restrict__ counts,
    int* __restrict__ refine_cnt, int* __restrict__ refine_pt) {
    __shared__ __align__(16) unsigned short As[2][128 * 64];
    __shared__ __align__(16) unsigned short Bs[2][128 * 64];
    __shared__ float x2s[128];
    __shared__ float v2s[512];
    __shared__ unsigned long long candk[128][2][2];
    int b = blockIdx.y;
    int n0 = blockIdx.x * 128;
    int tid = threadIdx.x;
    int wv = tid >> 6, lane = tid & 63;
    int wr = wv >> 1, wc = wv & 1;
    int quad = lane >> 4, l16 = lane & 15;
    const unsigned short* xb = xcat + ((size_t)b * N + n0) * 512;
    const unsigned short* vb0 = vcat + (size_t)b * K * 512;

    if (tid < 128) x2s[tid] = x2[b * N + n0 + tid];
    v2s[tid] = v2[b * K + tid];
    v2s[tid + 256] = v2[b * K + 256 + tid];

    // staging meta (r4-validated swizzle): fetch global chunk c into lds slot l
    int lds8[4], srow[4], schunk[4];
    #pragma unroll
    for (int i = 0; i < 4; i++) {
        int l = i * 256 + wv * 64 + lane;
        lds8[i] = l * 8;
        srow[i] = l >> 3;
        schunk[i] = ((l & 7) ^ ((l >> 3) & 7)) * 8;
    }

    float4v acc[4][4];
    #pragma unroll
    for (int i = 0; i < 4; i++)
        #pragma unroll
        for (int j = 0; j < 4; j++) acc[i][j] = (float4v){0.f, 0.f, 0.f, 0.f};

    // running top-2 u64 keys per (fi,r) row fragment
    unsigned long long k1[16], k2[16];
    #pragma unroll
    for (int i = 0; i < 16; i++) { k1[i] = ~0ull; k2[i] = ~0ull; }

    // kt schedule per chunk (r7/r8/r9-validated 12-step):
    //   A: xh 0-7, xl 8-11; B: vh 0-3, vl 4-7, vh 8-11
    // prologue: stage (ch=0, kt=0) into buffer 0
    #pragma unroll
    for (int i = 0; i < 4; i++) {
        gload_lds16(xb + (size_t)srow[i] * 512 + schunk[i], (void*)&As[0][lds8[i]]);
        gload_lds16(vb0 + (size_t)srow[i] * 512 + schunk[i], (void*)&Bs[0][lds8[i]]);
    }
    __syncthreads();   // vmcnt(0) drain: buffer 0 ready

    for (int ch = 0; ch < 4; ch++) {
        for (int kt = 0; kt < 12; kt++) {
            int cur = kt & 1;
            // prefetch next step (possibly next chunk's kt=0)
            int nkt = kt + 1, nch = ch;
            if (nkt == 12) { nkt = 0; nch++; }
            if (nch < 4) {
                int k4 = (nkt & 3) * 64;
                int kcolA = (nkt < 8) ? k4 : 256 + k4;
                int kcolB = (nkt < 4) ? k4 : ((nkt < 8) ? 256 + k4 : k4);
                const unsigned short* vbn = vb0 + (size_t)nch * (128 * 512);
                #pragma unroll
                for (int i = 0; i < 4; i++) {
                    gload_lds16(xb + (size_t)srow[i] * 512 + kcolA + schunk[i],
                                (void*)&As[1 - cur][lds8[i]]);
                    gload_lds16(vbn + (size_t)srow[i] * 512 + kcolB + schunk[i],
                                (void*)&Bs[1 - cur][lds8[i]]);
                }
            }
            #pragma unroll
            for (int ks = 0; ks < 2; ks++) {
                short8 af[4], bf[4];
                int ccr = ks * 4 + quad;
                #pragma unroll
                for (int f = 0; f < 4; f++) {
                    int rA = wr * 64 + f * 16 + l16;
                    af[f] = *(const short8*)&As[cur][(rA * 8 + (ccr ^ (rA & 7))) * 8];
                    int rB = wc * 64 + f * 16 + l16;
                    bf[f] = *(const short8*)&Bs[cur][(rB * 8 + (ccr ^ (rB & 7))) * 8];
                }
                #pragma unroll
                for (int fi = 0; fi < 4; fi++)
                    #pragma unroll
                    for (int fj = 0; fj < 4; fj++)
                        acc[fi][fj] = __builtin_amdgcn_mfma_f32_16x16x32_bf16(
                            af[fi], bf[fj], acc[fi][fj], 0, 0, 0);
            }
            __syncthreads();   // drains prefetch (next buffer ready) + all reads of cur done
        }
        // fold chunk ch into running top-2, reset acc (register-only; no barrier needed)
        #pragma unroll
        for (int fi = 0; fi < 4; fi++) {
            #pragma unroll
            for (int r = 0; r < 4; r++) {
                int lrow = wr * 64 + fi * 16 + quad * 4 + r;
                float x2v = x2s[lrow];
                int idx = fi * 4 + r;
                #pragma unroll
                for (int fj = 0; fj < 4; fj++) {
                    int cg = ch * 128 + wc * 64 + fj * 16 + l16;
                    float dist = fmaxf((x2v - 2.0f * acc[fi][fj][r]) + v2s[cg], 0.0f);
                    unsigned long long key =
                        ((unsigned long long)__float_as_uint(dist) << 32) | (unsigned)cg;
                    if (key < k1[idx]) { k2[idx] = k1[idx]; k1[idx] = key; }
                    else if (key < k2[idx]) { k2[idx] = key; }
                }
            }
        }
        #pragma unroll
        for (int fi = 0; fi < 4; fi++)
            #pragma unroll
            for (int fj = 0; fj < 4; fj++) acc[fi][fj] = (float4v){0.f, 0.f, 0.f, 0.f};
    }

    // final 16-lane butterfly merge per row fragment, once per block
    #pragma unroll
    for (int fi = 0; fi < 4; fi++) {
        #pragma unroll
        for (int r = 0; r < 4; r++) {
            int lrow = wr * 64 + fi * 16 + quad * 4 + r;
            int idx = fi * 4 + r;
            unsigned long long a1 = k1[idx], a2 = k2[idx];
            #pragma unroll
            for (int off = 1; off < 16; off <<= 1) {
                unsigned long long o1 = shfl_xor_u64(a1, off);
                unsigned long long o2 = shfl_xor_u64(a2, off);
                unsigned long long mx = a1 > o1 ? a1 : o1;
                a1 = a1 < o1 ? a1 : o1;
                unsigned long long mn2 = a2 < o2 ? a2 : o2;
                a2 = mx < mn2 ? mx : mn2;
            }
            if (l16 == 0) { candk[lrow][wc][0] = a1; candk[lrow][wc][1] = a2; }
        }
    }
    __syncthreads();
    if (tid < 128) {
        unsigned long long a1 = candk[tid][0][0], a2 = candk[tid][0][1];
        unsigned long long o1 = candk[tid][1][0], o2 = candk[tid][1][1];
        unsigned long long mx = a1 > o1 ? a1 : o1;
        unsigned long long b1 = a1 < o1 ? a1 : o1;
        unsigned long long mn2 = a2 < o2 ? a2 : o2;
        unsigned long long b2 = mx < mn2 ? mx : mn2;
        float bv1 = __uint_as_float((unsigned)(b1 >> 32));
        float bv2 = __uint_as_float((unsigned)(b2 >> 32));
        int bi1 = (int)(unsigned)(b1 & 0xffffffffull);
        int p = b * N + n0 + tid;
        assign[p] = bi1;
        atomicAdd(&counts[b * K + bi1], 1);
        // |dot err| <= xres*||v||max + ||x||*vresmax + xlo*vlomax (dropped xl*vl) [+ MFMA ~4e-4]
        float thr = 4.0f * (xres[p] * vmaxs[b] + sqrtf(x2s[tid]) * vresmaxs[b]
                            + xlo[p] * vlomaxs[b]) + 4e-3f;
        if (bv2 - bv1 < thr) {
            int pos = atomicAdd(refine_cnt, 1);
            refine_pt[pos] = p;
        }
    }
}

// exact fp32 rescan over ALL 512 centers for flagged points; fixes counts on change
__global__ __launch_bounds__(256) void k_rescan(
    const float* __restrict__ x, const float* __restrict__ vT,
    const float* __restrict__ x2, const float* __restrict__ v2,
    const int* __restrict__ refine_cnt, const int* __restrict__ refine_pt,
    int* __restrict__ assign, int* __restrict__ counts) {
    __shared__ float xs[256];
    __shared__ float rv[256];
    __shared__ int ri[256];
    int cnt = *refine_cnt;
    int t = threadIdx.x;
    for (int i = blockIdx.x; i < cnt; i += gridDim.x) {
        int p = refine_pt[i];
        int b = p >> 14;
        xs[t] = x[(size_t)p * D + t];
        __syncthreads();
        const float* vtb = vT + (size_t)b * D * K;
        float s0 = 0.f, s1 = 0.f;
        for (int d = 0; d < D; d++) {
            float xd = xs[d];
            s0 = fmaf(xd, vtb[(size_t)d * K + t], s0);
            s1 = fmaf(xd, vtb[(size_t)d * K + 256 + t], s1);
        }
        float x2p = x2[p];
        float d0 = fmaxf((x2p - 2.0f * s0) + v2[b * K + t], 0.0f);
        float d1 = fmaxf((x2p - 2.0f * s1) + v2[b * K + 256 + t], 0.0f);
        float bv; int bi;
        if (d1 < d0) { bv = d1; bi = t + 256; } else { bv = d0; bi = t; }
        rv[t] = bv; ri[t] = bi;
        __syncthreads();
        for (int s = 128; s; s >>= 1) {
            if (t < s) {
                if (rv[t + s] < rv[t] || (rv[t + s] == rv[t] && ri[t + s] < ri[t])) {
                    rv[t] = rv[t + s]; ri[t] = ri[t + s];
                }
            }
            __syncthreads();
        }
        if (t == 0) {
            int old = assign[p];
            int neu = ri[0];
            if (neu != old) {
                assign[p] = neu;
                atomicSub(&counts[b * K + old], 1);
                atomicAdd(&counts[b * K + neu], 1);
            }
        }
        __syncthreads();
    }
}

// =================== membership -> new centers (proven) ===================

__global__ __launch_bounds__(256) void k_scatter(
    const int* __restrict__ assign, const int* __restrict__ counts,
    int* __restrict__ cursor, int* __restrict__ order) {
    __shared__ int offs[K];
    int b = blockIdx.y;
    if (threadIdx.x < 64) {
        int lane = threadIdx.x;
        int pre[8]; int s = 0;
        #pragma unroll
        for (int j = 0; j < 8; j++) { pre[j] = s; s += counts[b * K + lane * 8 + j]; }
        int inc = s;
        #pragma unroll
        for (int off = 1; off < 64; off <<= 1) {
            int o = __shfl_up(inc, off);
            if (lane >= off) inc += o;
        }
        int excl = inc - s;
        #pragma unroll
        for (int j = 0; j < 8; j++) offs[lane * 8 + j] = excl + pre[j];
    }
    __syncthreads();
    int n = blockIdx.x * 256 + threadIdx.x;
    int a = assign[b * N + n];
    int pos = atomicAdd(&cursor[b * K + a], 1);
    order[b * N + offs[a] + pos] = n;
}

__global__ __launch_bounds__(256) void k_sumdiv(
    const float* __restrict__ x, const int* __restrict__ counts,
    const int* __restrict__ order, const float* __restrict__ totsum,
    float* __restrict__ v) {
    __shared__ int sh[256];
    __shared__ int ord[256];
    int t = threadIdx.x;
    int b = blockIdx.y, k = blockIdx.x;
    const int* cb = counts + b * K;
    int partial = 0;
    for (int j = t; j < k; j += 256) partial += cb[j];
    sh[t] = partial; __syncthreads();
    for (int s = 128; s; s >>= 1) { if (t < s) sh[t] += sh[t + s]; __syncthreads(); }
    int off = sh[0];
    int cnt = cb[k];
    const float* xb = x + (size_t)b * N * D;
    float acc = 0.f;
    for (int m0 = 0; m0 < cnt; m0 += 256) {
        int mm = min(256, cnt - m0);
        if (t < mm) ord[t] = order[b * N + off + m0 + t];
        __syncthreads();
        for (int m = 0; m < mm; m++) {
            int n = ord[m];
            acc += xb[(size_t)n * D + t];
        }
        __syncthreads();
    }
    float out;
    if (cnt > 0) out = acc * (1.0f / (float)cnt);
    else out = totsum[b * D + t];
    v[((size_t)b * K + k) * D + t] = out;
}

__global__ void k_write_u(const int* __restrict__ assign, float* __restrict__ uout) {
    int idx = blockIdx.x * 256 + threadIdx.x;
    int a = assign[idx];
    uout[(size_t)idx * K + a] = 1.0f;
}

__global__ void k_copy_v(const float* __restrict__ v, float* __restrict__ out) {
    int idx = blockIdx.x * 256 + threadIdx.x;
    ((float4*)out)[idx] = ((const float4*)v)[idx];
}

extern "C" void kernel_launch(void* const* d_in, const int* in_sizes, int n_in,
                              void* d_out, int out_size, void* d_ws, size_t ws_size,
                              hipStream_t stream) {
    const float* x = (const float*)d_in[0];
    float* out = (float*)d_out;
    char* ws = (char*)d_ws;

    // ---- ws: proven-small footprint (<3.0 MB) ----
    size_t off = 0;
    float* v      = (float*)(ws + off); off += (size_t)B * K * D * 4;
    float* x2     = (float*)(ws + off); off += (size_t)B * N * 4;
    float* v2     = (float*)(ws + off); off += (size_t)B * K * 4;
    float* totsum = (float*)(ws + off); off += (size_t)B * D * 4;
    int* assign   = (int*)(ws + off);   off += (size_t)B * N * 4;
    int* counts   = (int*)(ws + off);   off += (size_t)B * K * 4;   // counts+cursor contiguous
    int* cursor   = (int*)(ws + off);   off += (size_t)B * K * 4;
    int* order    = (int*)(ws + off);   off += (size_t)B * N * 4;
    int* inds     = (int*)(ws + off);   off += 4096;
    int* refine_cnt = (int*)(ws + off); off += 256;

    // ---- big scratch in d_out u-region (134 MB; proven home) ----
    char* ob = (char*)out;
    size_t oboff = 0;
    unsigned short* xcat = (unsigned short*)(ob + oboff); oboff += (size_t)B * N * 512 * 2;  // 64 MiB
    int* refine_pt = (int*)(ob + oboff);    oboff += (size_t)B * N * 4;                      // 256 KiB
    float* vT      = (float*)(ob + oboff);  oboff += (size_t)B * K * D * 4;                  // 2 MiB
    float* xres    = (float*)(ob + oboff);  oboff += (size_t)B * N * 4;                      // 256 KiB
    float* xlo     = (float*)(ob + oboff);  oboff += (size_t)B * N * 4;                      // 256 KiB
    float* vres    = (float*)(ob + oboff);  oboff += (size_t)B * K * 4;                      // 8 KiB
    float* vlo     = (float*)(ob + oboff);  oboff += (size_t)B * K * 4;                      // 8 KiB
    float* vmaxs   = (float*)(ob + oboff);  oboff += 256;
    float* vresmaxs = (float*)(ob + oboff); oboff += 256;
    float* vlomaxs = (float*)(ob + oboff);  oboff += 256;
    unsigned short* vcat = (unsigned short*)(out + (size_t)B * N * K);  // v-region, 2 MiB exact

    static int h_inds[K];
    host_sample_inds(h_inds);
    hipMemcpyAsync(inds, h_inds, K * sizeof(int), hipMemcpyHostToDevice, stream);

    hipMemsetAsync(totsum, 0, (size_t)B * D * 4, stream);
    k_gather_v0<<<B * K, 64, 0, stream>>>(x, inds, v);
    k_totsum<<<dim3(64, B), 256, 0, stream>>>(x, totsum);
    k_prep<<<(B * N) / 4, 256, 0, stream>>>(x, xcat, x2, xres, xlo);

    for (int it = 0; it < ITERS; it++) {
        k_prep<<<(B * K) / 4, 256, 0, stream>>>(v, vcat, v2, vres, vlo);
        k_errmax<<<B, 256, 0, stream>>>(v2, vres, vlo, vmaxs, vresmaxs, vlomaxs);
        k_transpose<<<(B * K * D) / 256, 256, 0, stream>>>(v, vT);
        hipMemsetAsync(refine_cnt, 0, 256, stream);
        hipMemsetAsync(counts, 0, 2 * (size_t)B * K * 4, stream);  // counts + cursor
        k_gemm_assign<<<dim3(N / 128, B), 256, 0, stream>>>(
            xcat, vcat, x2, v2, xres, xlo, vmaxs, vresmaxs, vlomaxs,
            assign, counts, refine_cnt, refine_pt);
        k_rescan<<<1024, 256, 0, stream>>>(x, vT, x2, v2, refine_cnt, refine_pt,
                                           assign, counts);
        k_scatter<<<dim3(N / 256, B), 256, 0, stream>>>(assign, counts, cursor, order);
        k_sumdiv<<<dim3(K, B), 256, 0, stream>>>(x, counts, order, totsum, v);
    }

    hipMemsetAsync(out, 0, (size_t)B * N * K * 4, stream);
    k_write_u<<<(B * N) / 256, 256, 0, stream>>>(assign, out);
    k_copy_v<<<(B * K * D) / 1024, 256, 0, stream>>>(v, out + (size_t)B * N * K);
}